// Round 5
// baseline (931.877 us; speedup 1.0000x reference)
//
#include <hip/hip_runtime.h>
#include <math.h>

// Problem constants
constexpr int kB = 4, kG = 2048, kD = 256, kH = 8, kHD = 32, kL = 4, kFFN = 1024;
constexpr int kBG = kB * kG;                  // 8192 tokens
constexpr int kCHUNK = 64;                    // linear-attn chunk length
constexpr int kNC = kG / kCHUNK;              // 32 chunks per sequence
constexpr int kSUMSZ = kHD * kHD + kHD;       // 1056 floats per chunk-state
constexpr int kQKVN = 3 * kD;                 // 768 fused QKV columns

typedef __bf16 bf16x8 __attribute__((ext_vector_type(8)));
typedef unsigned short ushort8 __attribute__((ext_vector_type(8)));
typedef float floatx4 __attribute__((ext_vector_type(4)));

__device__ __forceinline__ unsigned short f2bf(float f) {
  unsigned int u = __float_as_uint(f);
  u += 0x7fff + ((u >> 16) & 1);              // round-to-nearest-even
  return (unsigned short)(u >> 16);
}

__device__ __forceinline__ void load_lds_16(const void* g, void* l) {
  __builtin_amdgcn_global_load_lds((const __attribute__((address_space(1))) void*)g,
                                   (__attribute__((address_space(3))) void*)l,
                                   16, 0, 0);
}

// ---------------------------------------------------------------------------
// h[b,g,d] = gene_emb[g,d] + ree(x[b,g], d)
__global__ void embed_kernel(const float* __restrict__ x,
                             const float* __restrict__ ge,
                             float* __restrict__ h) {
  int idx = blockIdx.x * 256 + threadIdx.x;   // over kB*kG*kD = 2^21
  int d = idx & (kD - 1);
  int g = (idx >> 8) & (kG - 1);
  int b = idx >> 19;
  float xv = x[b * kG + g];
  int i = d & 127;
  float inv = expf(-(float)i * (4.6051701859880914f / 128.0f));  // 100^(-i/128)
  float f = xv * inv;
  float r = (d < 128) ? sinf(f) : cosf(f);
  if (xv == -10.0f) r = 0.0f;
  h[idx] = ge[g * kD + d] + r;
}

// ---------------------------------------------------------------------------
// Weight conversion: fp32 K-major -> bf16 N-major (transposed), plus QKV bias
// packing. One launch covers all layers.
__global__ void convert_weights_kernel(
    const float* __restrict__ Wq, const float* __restrict__ Wk,
    const float* __restrict__ Wv, const float* __restrict__ WU,
    const float* __restrict__ WV, const float* __restrict__ bq,
    const float* __restrict__ bk, const float* __restrict__ bv,
    unsigned short* __restrict__ Wqkv_t, unsigned short* __restrict__ WU_t,
    unsigned short* __restrict__ WV_t, float* __restrict__ bias_qkv) {
  int blk = blockIdx.x;
  if (blk >= kL * 704) {                       // bias-packing tail blocks
    int idx = (blk - kL * 704) * 256 + threadIdx.x;
    if (idx < kL * kQKVN) {
      int l = idx / kQKVN, n = idx % kQKVN;
      float v = (n < 256) ? bq[l * 256 + n]
              : (n < 512) ? bk[l * 256 + n - 256]
                          : bv[l * 256 + n - 512];
      bias_qkv[idx] = v;
    }
    return;
  }
  int l = blk / 704, id = blk % 704;
  const float* src;
  unsigned short* dst;
  int Ksrc, Nsrc, kt, nt;
  if (id < 192) {
    int m = id >> 6, tid = id & 63;
    src = (m == 0 ? Wq : m == 1 ? Wk : Wv) + (size_t)l * 256 * 256;
    dst = Wqkv_t + (size_t)l * kQKVN * 256 + (size_t)m * 256 * 256;
    Ksrc = 256; Nsrc = 256; kt = tid >> 3; nt = tid & 7;
  } else if (id < 448) {
    int tid = id - 192;
    src = WU + (size_t)l * 256 * 1024;
    dst = WU_t + (size_t)l * 1024 * 256;
    Ksrc = 256; Nsrc = 1024; kt = tid >> 5; nt = tid & 31;
  } else {
    int tid = id - 448;
    src = WV + (size_t)l * 1024 * 256;
    dst = WV_t + (size_t)l * 256 * 1024;
    Ksrc = 1024; Nsrc = 256; kt = tid >> 3; nt = tid & 7;
  }
  __shared__ float s[32][33];
  int tx = threadIdx.x & 31, ty = threadIdx.x >> 5;   // 32 x 8
#pragma unroll
  for (int r = 0; r < 4; r++)
    s[ty + r * 8][tx] = src[(size_t)(kt * 32 + ty + r * 8) * Nsrc + nt * 32 + tx];
  __syncthreads();
#pragma unroll
  for (int r = 0; r < 4; r++)
    dst[(size_t)(nt * 32 + ty + r * 8) * Ksrc + kt * 32 + tx] =
        f2bf(s[tx][ty + r * 8]);
}

// ---------------------------------------------------------------------------
// bf16 MFMA GEMM, 64x64 tile, full-K staging (one barrier per 256-deep K
// chunk, 32 MFMAs between barriers — AITER-style density).
// LNFUSE: A-side = fp32 h, LayerNorm computed in-kernel (K == D == full row),
//         bf16 written to LDS via ds_write (stride-40 rows: 16B-aligned,
//         2-way bank residue = free).
// !LNFUSE: A-side = bf16 (row-major MxK), staged via global_load_lds.
// EPI: 1 = fused QKV (square cols < 512), fp32 out
//      2 = exact gelu, bf16 out
//      3 = residual add (Cres == C), fp32 out
template <int EPI, bool LNFUSE, int KTOT>
__global__ __launch_bounds__(256) void mfma_gemm(
    const unsigned short* __restrict__ A, const float* __restrict__ Af,
    const unsigned short* __restrict__ Bt, const float* __restrict__ bias,
    const float* __restrict__ gamma, const float* __restrict__ beta,
    void* __restrict__ Cout, const float* __restrict__ Cres, int M, int N) {
  constexpr int AST = LNFUSE ? 40 : 32;       // LDS A row stride (elems)
  constexpr int ACH = 64 * AST;               // elems per 64x32 A k-chunk
  __shared__ unsigned short As[8 * ACH];      // 40 KB (LN) / 32 KB
  __shared__ unsigned short Bs[8 * 64 * 32];  // 32 KB
  const int t = threadIdx.x;
  const int w = t >> 6, lane = t & 63;
  const int bm = blockIdx.y * 64, bn = blockIdx.x * 64;
  const int wm = (w >> 1) * 32, wn = (w & 1) * 32;
  const int srow = lane >> 2;            // 0..15 within 16-row chunk
  const int skof = (lane & 3) * 8;       // k element offset of 16B piece

  floatx4 acc[2][2];
#pragma unroll
  for (int i = 0; i < 2; i++)
#pragma unroll
    for (int j = 0; j < 2; j++) acc[i][j] = (floatx4){0.f, 0.f, 0.f, 0.f};

  const int lm = lane & 15, lq = lane >> 4;

  for (int k0 = 0; k0 < KTOT; k0 += 256) {
    if (k0) __syncthreads();                  // LDS reuse across K super-steps
    // --- stage B: wave w covers rows w*16..+15 of all 8 k-chunks ---
    const unsigned short* bp =
        Bt + (size_t)(bn + w * 16 + srow) * KTOT + k0 + skof;
#pragma unroll
    for (int kc = 0; kc < 8; kc++)
      load_lds_16(bp + kc * 32, &Bs[kc * 2048 + w * 512]);
    // --- stage A ---
    if (LNFUSE) {
      // thread t: row t>>2, cols (t&3)*64..+63 (quad of lanes shares a row)
      int row = t >> 2, cg = t & 3;
      const float* hp = Af + (size_t)(bm + row) * 256 + cg * 64;
      float va[64];
#pragma unroll
      for (int i = 0; i < 16; i++)
        *(float4*)&va[i * 4] = *(const float4*)&hp[i * 4];
      float s = 0, sq = 0;
#pragma unroll
      for (int i = 0; i < 64; i++) { s += va[i]; sq += va[i] * va[i]; }
      s += __shfl_xor(s, 1);  s += __shfl_xor(s, 2);
      sq += __shfl_xor(sq, 1); sq += __shfl_xor(sq, 2);
      float mu = s * (1.0f / kD);
      float var = sq * (1.0f / kD) - mu * mu;
      float rr = rsqrtf(var + 1e-5f);
#pragma unroll
      for (int i = 0; i < 16; i++) {
        float4 g4 = *(const float4*)&gamma[cg * 64 + i * 4];
        float4 b4 = *(const float4*)&beta[cg * 64 + i * 4];
        va[i * 4 + 0] = (va[i * 4 + 0] - mu) * rr * g4.x + b4.x;
        va[i * 4 + 1] = (va[i * 4 + 1] - mu) * rr * g4.y + b4.y;
        va[i * 4 + 2] = (va[i * 4 + 2] - mu) * rr * g4.z + b4.z;
        va[i * 4 + 3] = (va[i * 4 + 3] - mu) * rr * g4.w + b4.w;
      }
#pragma unroll
      for (int half = 0; half < 2; half++) {
        int chunk = cg * 2 + half;
        unsigned short* dst = &As[chunk * ACH + row * AST];
#pragma unroll
        for (int gi = 0; gi < 4; gi++) {
          ushort8 pk;
#pragma unroll
          for (int e = 0; e < 8; e++)
            pk[e] = f2bf(va[half * 32 + gi * 8 + e]);
          *(ushort8*)&dst[gi * 8] = pk;
        }
      }
    } else {
      const unsigned short* ap =
          A + (size_t)(bm + w * 16 + srow) * KTOT + k0 + skof;
#pragma unroll
      for (int kc = 0; kc < 8; kc++)
        load_lds_16(ap + kc * 32, &As[kc * ACH + w * 512]);
    }
    __syncthreads();                          // one drain per 256-deep K step
    // --- compute: 8 k-chunks x 4 MFMAs ---
#pragma unroll
    for (int kc = 0; kc < 8; kc++) {
      const unsigned short* afp = &As[kc * ACH + (wm + lm) * AST + lq * 8];
      const unsigned short* bfp = &Bs[kc * 2048 + (wn + lm) * 32 + lq * 8];
      bf16x8 af[2], bfr[2];
#pragma unroll
      for (int i = 0; i < 2; i++)
        af[i] = __builtin_bit_cast(bf16x8,
            *reinterpret_cast<const ushort8*>(afp + i * 16 * AST));
#pragma unroll
      for (int j = 0; j < 2; j++)
        bfr[j] = __builtin_bit_cast(bf16x8,
            *reinterpret_cast<const ushort8*>(bfp + j * 16 * 32));
#pragma unroll
      for (int i = 0; i < 2; i++)
#pragma unroll
        for (int j = 0; j < 2; j++)
          acc[i][j] = __builtin_amdgcn_mfma_f32_16x16x32_bf16(af[i], bfr[j],
                                                              acc[i][j], 0, 0, 0);
    }
  }

  // Epilogue. C/D layout: col = lane&15, row = (lane>>4)*4 + reg.
  const int r0 = bm + wm + lq * 4;
  const int c0 = bn + wn + lm;
#pragma unroll
  for (int j = 0; j < 2; j++) {
    int col = c0 + j * 16;
    float bv = bias[col];
#pragma unroll
    for (int i = 0; i < 2; i++) {
      int rowb = r0 + i * 16;
#pragma unroll
      for (int r = 0; r < 4; r++) {
        int row = rowb + r;
        float v = acc[i][j][r] + bv;
        size_t idx = (size_t)row * N + col;
        if (EPI == 1) {
          ((float*)Cout)[idx] = (col < 512) ? v * v : v;
        } else if (EPI == 2) {
          float g = 0.5f * v * (1.0f + erff(v * 0.70710678118654752f));
          ((unsigned short*)Cout)[idx] = f2bf(g);
        } else {
          ((float*)Cout)[idx] = Cres[idx] + v;
        }
      }
    }
  }
}

// ---------------------------------------------------------------------------
// Per-chunk summaries from fused qkv buffer (row stride 768).
__global__ __launch_bounds__(256) void attn_sums_kernel(
    const float* __restrict__ qkv, float* __restrict__ sums) {
  int blk = blockIdx.x;              // b*(H*NC) + h*NC + c
  int c = blk & (kNC - 1);
  int hh = (blk >> 5) & (kH - 1);
  int b = blk >> 8;
  int g0 = c * kCHUNK;
  __shared__ float ks[kCHUNK][kHD];
  __shared__ float vs[kCHUNK][kHD];
  const float* kbase = qkv + (size_t)(b * kG + g0) * kQKVN + 256 + hh * kHD;
  const float* vbase = qkv + (size_t)(b * kG + g0) * kQKVN + 512 + hh * kHD;
#pragma unroll
  for (int r = 0; r < 2; r++) {
    int e = threadIdx.x + r * 256;
    int i = e >> 3, j = (e & 7) * 4;
    *(float4*)&ks[i][j] = *(const float4*)&kbase[(size_t)i * kQKVN + j];
    *(float4*)&vs[i][j] = *(const float4*)&vbase[(size_t)i * kQKVN + j];
  }
  __syncthreads();
  int m = threadIdx.x >> 3, n0 = (threadIdx.x & 7) * 4;
  float a0 = 0, a1 = 0, a2 = 0, a3 = 0;
  for (int i = 0; i < kCHUNK; i++) {
    float km = ks[i][m];
    float4 v4 = *(const float4*)&vs[i][n0];
    a0 = fmaf(km, v4.x, a0); a1 = fmaf(km, v4.y, a1);
    a2 = fmaf(km, v4.z, a2); a3 = fmaf(km, v4.w, a3);
  }
  float* outp = sums + (size_t)blk * kSUMSZ;
  *(float4*)&outp[m * kHD + n0] = make_float4(a0, a1, a2, a3);
  if (threadIdx.x < kHD) {
    float s = 0;
    for (int i = 0; i < kCHUNK; i++) s += ks[i][threadIdx.x];
    outp[kHD * kHD + threadIdx.x] = s;
  }
}

// ---------------------------------------------------------------------------
// Per-chunk output: o = (QK^T masked)·V + Q·S_prev, normalized; h += o.
// Chunk-prefix (exclusive scan over predecessor chunk states) is folded in:
// each block reduces sums[bh][0..c-1] with coalesced L2 reads — removes the
// separate scan kernel + its launch dependency.
__global__ __launch_bounds__(256) void attn_out_kernel(
    const float* __restrict__ qkv, const float* __restrict__ sums,
    float* __restrict__ h) {
  int blk = blockIdx.x;
  int c = blk & (kNC - 1);
  int hh = (blk >> 5) & (kH - 1);
  int b = blk >> 8;
  int g0 = c * kCHUNK;
  __shared__ float qs[kCHUNK][36];
  __shared__ float ks[kCHUNK][36];
  __shared__ float vs[kCHUNK][36];
  __shared__ float Sf[kHD][kHD];
  __shared__ float ksum[kHD];
  __shared__ float dinv_s[kCHUNK];
  __shared__ float Amat[kCHUNK][68];
  int t = threadIdx.x;
  const float* base = qkv + (size_t)(b * kG + g0) * kQKVN + hh * kHD;
#pragma unroll
  for (int r = 0; r < 2; r++) {
    int e = t + r * 256;
    int i = e >> 3, j = (e & 7) * 4;
    *(float4*)&qs[i][j] = *(const float4*)&base[(size_t)i * kQKVN + j];
    *(float4*)&ks[i][j] = *(const float4*)&base[(size_t)i * kQKVN + 256 + j];
    *(float4*)&vs[i][j] = *(const float4*)&base[(size_t)i * kQKVN + 512 + j];
  }
  // Exclusive prefix of chunk states 0..c-1 (each thread strides kSUMSZ).
  {
    float accv[5] = {0.f, 0.f, 0.f, 0.f, 0.f};
    const float* pb = sums + (size_t)((b * kH + hh) * kNC) * kSUMSZ;
    for (int cc = 0; cc < c; cc++) {
      const float* pc = pb + (size_t)cc * kSUMSZ;
#pragma unroll
      for (int r = 0; r < 5; r++) {
        int e = r * 256 + t;
        if (e < kSUMSZ) accv[r] += pc[e];
      }
    }
#pragma unroll
    for (int r = 0; r < 5; r++) {
      int e = r * 256 + t;
      if (e < 1024) ((float*)Sf)[e] = accv[r];
      else if (e < kSUMSZ) ksum[e - 1024] = accv[r];
    }
  }
  __syncthreads();

  // Stage 1: Amat[i][j] = q_i . k_j, plus den_i folded in.
  {
    int i = t >> 2, jb = t & 3;
    float qr[kHD];
#pragma unroll
    for (int m4 = 0; m4 < kHD / 4; m4++) {
      float4 qv = *(const float4*)&qs[i][m4 * 4];
      qr[m4 * 4 + 0] = qv.x; qr[m4 * 4 + 1] = qv.y;
      qr[m4 * 4 + 2] = qv.z; qr[m4 * 4 + 3] = qv.w;
    }
    float psum = 0.0f;
#pragma unroll
    for (int jj = 0; jj < 16; jj++) {
      int j = jb + jj * 4;
      float s = 0;
#pragma unroll
      for (int m4 = 0; m4 < kHD / 4; m4++) {
        float4 kv = *(const float4*)&ks[j][m4 * 4];
        s = fmaf(qr[m4 * 4 + 0], kv.x, s);
        s = fmaf(qr[m4 * 4 + 1], kv.y, s);
        s = fmaf(qr[m4 * 4 + 2], kv.z, s);
        s = fmaf(qr[m4 * 4 + 3], kv.w, s);
      }
      Amat[i][j] = s;
      if (j <= i) psum += s;
    }
    psum += __shfl_xor(psum, 1);
    psum += __shfl_xor(psum, 2);
    if (jb == 0) {
      float dk = 0;
#pragma unroll
      for (int m = 0; m < kHD; m++) dk = fmaf(qr[m], ksum[m], dk);
      dinv_s[i] = 1.0f / (psum + dk + 1e-16f);
    }
  }
  __syncthreads();

  // Stage 2: num_i[n] = sum_{j<=i} A[i][j] v_j[n] + q_i . S ; h += num * dinv
  float* hbase = h + (size_t)(b * kG + g0) * kD + hh * kHD;
#pragma unroll
  for (int uu = 0; uu < 2; uu++) {
    int u = t + uu * 256;
    int i = u >> 3, n0 = (u & 7) * 4;
    float ax = 0, ay = 0, az = 0, aw = 0;
#pragma unroll
    for (int m = 0; m < kHD; m++) {
      float qm = qs[i][m];
      float4 s4 = *(const float4*)&Sf[m][n0];
      ax = fmaf(qm, s4.x, ax); ay = fmaf(qm, s4.y, ay);
      az = fmaf(qm, s4.z, az); aw = fmaf(qm, s4.w, aw);
    }
    for (int j = 0; j <= i; j++) {
      float w = Amat[i][j];
      float4 vv = *(const float4*)&vs[j][n0];
      ax = fmaf(w, vv.x, ax); ay = fmaf(w, vv.y, ay);
      az = fmaf(w, vv.z, az); aw = fmaf(w, vv.w, aw);
    }
    float dinv = dinv_s[i];
    float* hp = hbase + (size_t)i * kD + n0;
    float4 old = *(const float4*)hp;
    *(float4*)hp = make_float4(old.x + ax * dinv, old.y + ay * dinv,
                               old.z + az * dinv, old.w + aw * dinv);
  }
}

// ---------------------------------------------------------------------------
// out[row] = h[row,:] . Wo + bo. Wave-per-row, 4 rows/block.
__global__ __launch_bounds__(256) void final_kernel(
    const float* __restrict__ h, const float* __restrict__ Wo,
    const float* __restrict__ bo, float* __restrict__ out) {
  int w = threadIdx.x >> 6, lane = threadIdx.x & 63;
  size_t row = (size_t)blockIdx.x * 4 + w;
  float4 hv = *(const float4*)&h[row * kD + lane * 4];
  float4 wv = *(const float4*)&Wo[lane * 4];
  float s = hv.x * wv.x + hv.y * wv.y + hv.z * wv.z + hv.w * wv.w;
#pragma unroll
  for (int o = 32; o > 0; o >>= 1) s += __shfl_xor(s, o);
  if (lane == 0) out[row] = s + bo[0];
}

// ---------------------------------------------------------------------------
extern "C" void kernel_launch(void* const* d_in, const int* in_sizes, int n_in,
                              void* d_out, int out_size, void* d_ws, size_t ws_size,
                              hipStream_t stream) {
  const float* x    = (const float*)d_in[0];
  const float* ge   = (const float*)d_in[1];
  const float* Wq   = (const float*)d_in[2];
  const float* bq   = (const float*)d_in[3];
  const float* Wk   = (const float*)d_in[4];
  const float* bk   = (const float*)d_in[5];
  const float* Wv   = (const float*)d_in[6];
  const float* bv   = (const float*)d_in[7];
  const float* ln1g = (const float*)d_in[8];
  const float* ln1b = (const float*)d_in[9];
  const float* ln2g = (const float*)d_in[10];
  const float* ln2b = (const float*)d_in[11];
  const float* WU   = (const float*)d_in[12];
  const float* bU   = (const float*)d_in[13];
  const float* WV   = (const float*)d_in[14];
  const float* bV   = (const float*)d_in[15];
  const float* Wo   = (const float*)d_in[16];
  const float* bo   = (const float*)d_in[17];
  float* out = (float*)d_out;

  // Workspace layout (fp32 slot offsets; all 16B-aligned):
  float* ws = (float*)d_ws;
  float*          h       = ws;                        // 2,097,152 f32
  float*          qkv     = ws + 3145728;              // 6,291,456 f32 [8192][768]
  unsigned short* u       = (unsigned short*)qkv;      // aliases qkv (disjoint phases)
  float*          sums    = ws + 9437184;              // 1,081,344 f32
  unsigned short* Wqkv_t  = (unsigned short*)(ws + 10518528);  // 786,432 bf16
  unsigned short* WU_t    = (unsigned short*)(ws + 10911744);  // 1,048,576 bf16
  unsigned short* WV_t    = (unsigned short*)(ws + 11436032);  // 1,048,576 bf16
  float*          bias_qkv= ws + 11960320;             // 3,072 f32

  dim3 blk256(256);
  convert_weights_kernel<<<kL * 704 + 12, blk256, 0, stream>>>(
      Wq, Wk, Wv, WU, WV, bq, bk, bv, Wqkv_t, WU_t, WV_t, bias_qkv);
  embed_kernel<<<kBG * kD / 256, blk256, 0, stream>>>(x, ge, h);
  for (int l = 0; l < kL; l++) {
    // QKV GEMM with fused LN1 (A = h fp32, LN in-kernel)
    mfma_gemm<1, true, 256><<<dim3(kQKVN / 64, kBG / 64), blk256, 0, stream>>>(
        nullptr, h, Wqkv_t + (size_t)l * kQKVN * kD, bias_qkv + l * kQKVN,
        ln1g + l * kD, ln1b + l * kD, qkv, nullptr, kBG, kQKVN);
    attn_sums_kernel<<<kB * kH * kNC, blk256, 0, stream>>>(qkv, sums);
    attn_out_kernel<<<kB * kH * kNC, blk256, 0, stream>>>(qkv, sums, h);
    // FFN1 GEMM with fused LN2 + gelu epilogue
    mfma_gemm<2, true, 256><<<dim3(kFFN / 64, kBG / 64), blk256, 0, stream>>>(
        nullptr, h, WU_t + (size_t)l * kFFN * kD, bU + l * kFFN,
        ln2g + l * kD, ln2b + l * kD, u, nullptr, kBG, kFFN);
    // FFN2 GEMM (A = u bf16), residual add
    mfma_gemm<3, false, 1024><<<dim3(kD / 64, kBG / 64), blk256, 0, stream>>>(
        u, nullptr, WV_t + (size_t)l * kD * kFFN, bV + l * kD,
        nullptr, nullptr, h, h, kBG, kD);
  }
  final_kernel<<<kBG / 4, blk256, 0, stream>>>(h, Wo, bo, out);
}

// Round 6
// 425.151 us; speedup vs baseline: 2.1919x; 2.1919x over previous
//
#include <hip/hip_runtime.h>
#include <math.h>

// Problem constants
constexpr int kB = 4, kG = 2048, kD = 256, kH = 8, kHD = 32, kL = 4, kFFN = 1024;
constexpr int kBG = kB * kG;                  // 8192 tokens
constexpr int kCHUNK = 64;                    // linear-attn chunk length
constexpr int kNC = kG / kCHUNK;              // 32 chunks per sequence
constexpr int kSUMSZ = kHD * kHD + kHD;       // 1056 floats per chunk-state
constexpr int kQKVN = 3 * kD;                 // 768 fused QKV columns

typedef __bf16 bf16x8 __attribute__((ext_vector_type(8)));
typedef unsigned short ushort8 __attribute__((ext_vector_type(8)));
typedef float floatx4 __attribute__((ext_vector_type(4)));

__device__ __forceinline__ unsigned short f2bf(float f) {
  unsigned int u = __float_as_uint(f);
  u += 0x7fff + ((u >> 16) & 1);              // round-to-nearest-even
  return (unsigned short)(u >> 16);
}

__device__ __forceinline__ void load_lds_16(const void* g, void* l) {
  __builtin_amdgcn_global_load_lds((const __attribute__((address_space(1))) void*)g,
                                   (__attribute__((address_space(3))) void*)l,
                                   16, 0, 0);
}

// ---------------------------------------------------------------------------
// h[b,g,d] = gene_emb[g,d] + ree(x[b,g], d)
__global__ void embed_kernel(const float* __restrict__ x,
                             const float* __restrict__ ge,
                             float* __restrict__ h) {
  int idx = blockIdx.x * 256 + threadIdx.x;   // over kB*kG*kD = 2^21
  int d = idx & (kD - 1);
  int g = (idx >> 8) & (kG - 1);
  int b = idx >> 19;
  float xv = x[b * kG + g];
  int i = d & 127;
  float inv = expf(-(float)i * (4.6051701859880914f / 128.0f));  // 100^(-i/128)
  float f = xv * inv;
  float r = (d < 128) ? sinf(f) : cosf(f);
  if (xv == -10.0f) r = 0.0f;
  h[idx] = ge[g * kD + d] + r;
}

// ---------------------------------------------------------------------------
// Weight conversion: fp32 K-major -> bf16 N-major (transposed), plus QKV bias
// packing. One launch covers all layers.
__global__ void convert_weights_kernel(
    const float* __restrict__ Wq, const float* __restrict__ Wk,
    const float* __restrict__ Wv, const float* __restrict__ WU,
    const float* __restrict__ WV, const float* __restrict__ bq,
    const float* __restrict__ bk, const float* __restrict__ bv,
    unsigned short* __restrict__ Wqkv_t, unsigned short* __restrict__ WU_t,
    unsigned short* __restrict__ WV_t, float* __restrict__ bias_qkv) {
  int blk = blockIdx.x;
  if (blk >= kL * 704) {                       // bias-packing tail blocks
    int idx = (blk - kL * 704) * 256 + threadIdx.x;
    if (idx < kL * kQKVN) {
      int l = idx / kQKVN, n = idx % kQKVN;
      float v = (n < 256) ? bq[l * 256 + n]
              : (n < 512) ? bk[l * 256 + n - 256]
                          : bv[l * 256 + n - 512];
      bias_qkv[idx] = v;
    }
    return;
  }
  int l = blk / 704, id = blk % 704;
  const float* src;
  unsigned short* dst;
  int Ksrc, Nsrc, kt, nt;
  if (id < 192) {
    int m = id >> 6, tid = id & 63;
    src = (m == 0 ? Wq : m == 1 ? Wk : Wv) + (size_t)l * 256 * 256;
    dst = Wqkv_t + (size_t)l * kQKVN * 256 + (size_t)m * 256 * 256;
    Ksrc = 256; Nsrc = 256; kt = tid >> 3; nt = tid & 7;
  } else if (id < 448) {
    int tid = id - 192;
    src = WU + (size_t)l * 256 * 1024;
    dst = WU_t + (size_t)l * 1024 * 256;
    Ksrc = 256; Nsrc = 1024; kt = tid >> 5; nt = tid & 31;
  } else {
    int tid = id - 448;
    src = WV + (size_t)l * 1024 * 256;
    dst = WV_t + (size_t)l * 256 * 1024;
    Ksrc = 1024; Nsrc = 256; kt = tid >> 3; nt = tid & 7;
  }
  __shared__ float s[32][33];
  int tx = threadIdx.x & 31, ty = threadIdx.x >> 5;   // 32 x 8
#pragma unroll
  for (int r = 0; r < 4; r++)
    s[ty + r * 8][tx] = src[(size_t)(kt * 32 + ty + r * 8) * Nsrc + nt * 32 + tx];
  __syncthreads();
#pragma unroll
  for (int r = 0; r < 4; r++)
    dst[(size_t)(nt * 32 + ty + r * 8) * Ksrc + kt * 32 + tx] =
        f2bf(s[tx][ty + r * 8]);
}

// ---------------------------------------------------------------------------
// Row LayerNorm over D=256 -> bf16 output. Wave-per-row, 4 rows/block.
__global__ __launch_bounds__(256) void ln_kernel(
    const float* __restrict__ h, const float* __restrict__ gamma,
    const float* __restrict__ beta, unsigned short* __restrict__ z) {
  int w = threadIdx.x >> 6, lane = threadIdx.x & 63;
  size_t row = (size_t)blockIdx.x * 4 + w;
  float4 v = *(const float4*)&h[row * kD + lane * 4];
  float s = v.x + v.y + v.z + v.w;
  float sq = v.x * v.x + v.y * v.y + v.z * v.z + v.w * v.w;
#pragma unroll
  for (int o = 32; o > 0; o >>= 1) {
    s += __shfl_xor(s, o);
    sq += __shfl_xor(sq, o);
  }
  float mu = s * (1.0f / kD);
  float var = sq * (1.0f / kD) - mu * mu;
  float r = rsqrtf(var + 1e-5f);
  float4 g4 = *(const float4*)&gamma[lane * 4];
  float4 b4 = *(const float4*)&beta[lane * 4];
  float y0 = (v.x - mu) * r * g4.x + b4.x;
  float y1 = (v.y - mu) * r * g4.y + b4.y;
  float y2 = (v.z - mu) * r * g4.z + b4.z;
  float y3 = (v.w - mu) * r * g4.w + b4.w;
  unsigned int u0 = (unsigned int)f2bf(y0) | ((unsigned int)f2bf(y1) << 16);
  unsigned int u1 = (unsigned int)f2bf(y2) | ((unsigned int)f2bf(y3) << 16);
  uint2 uu; uu.x = u0; uu.y = u1;
  *(uint2*)&z[row * kD + lane * 4] = uu;
}

// ---------------------------------------------------------------------------
// bf16 MFMA GEMM, 64x64 tile, BK=32 DOUBLE-BUFFERED (16 KB LDS).
// One barrier per K-step (vs 2 in the round-4 version): step s+1's
// global_load_lds issues before compute(s); the barrier's implicit vmcnt(0)
// drains it, with 8 blocks/CU of waves covering the residual latency.
// A: M x K bf16 (row-major), Bt: N x K bf16 (row-major = W transposed).
// EPI: 1 = fused QKV (square cols < 512), fp32 out
//      2 = exact gelu, bf16 out
//      3 = residual add (Cres == C), fp32 out
template <int EPI>
__global__ __launch_bounds__(256) void mfma_gemm(
    const unsigned short* __restrict__ A, const unsigned short* __restrict__ Bt,
    const float* __restrict__ bias, void* __restrict__ Cout,
    const float* __restrict__ Cres, int M, int N, int K) {
  __shared__ unsigned short As[2][64 * 32];   // 2 x 4 KB
  __shared__ unsigned short Bs[2][64 * 32];   // 2 x 4 KB
  const int t = threadIdx.x;
  const int w = t >> 6, lane = t & 63;
  const int bm = blockIdx.y * 64, bn = blockIdx.x * 64;
  const int wm = (w >> 1) * 32, wn = (w & 1) * 32;

  // Staging: wave w fills rows w*16..w*16+15 of both tiles (1 KB per load).
  const int srow = lane >> 2;            // 0..15 within chunk
  const int skof = (lane & 3) * 8;       // k element offset of 16B piece
  const unsigned short* ap = A + (size_t)(bm + w * 16 + srow) * K + skof;
  const unsigned short* bp = Bt + (size_t)(bn + w * 16 + srow) * K + skof;

  floatx4 acc[2][2];
#pragma unroll
  for (int i = 0; i < 2; i++)
#pragma unroll
    for (int j = 0; j < 2; j++) acc[i][j] = (floatx4){0.f, 0.f, 0.f, 0.f};

  const int lm = lane & 15, lq = lane >> 4;
  const int nsteps = K >> 5;

  // Prologue: stage step 0 into buffer 0.
  load_lds_16(ap, &As[0][w * 512]);
  load_lds_16(bp, &Bs[0][w * 512]);
  __syncthreads();

  for (int s = 0; s < nsteps; s++) {
    const int cur = s & 1, nxt = cur ^ 1;
    if (s + 1 < nsteps) {                     // prefetch next step
      load_lds_16(ap + (s + 1) * 32, &As[nxt][w * 512]);
      load_lds_16(bp + (s + 1) * 32, &Bs[nxt][w * 512]);
    }
    const unsigned short* afp = &As[cur][(wm + lm) * 32 + lq * 8];
    const unsigned short* bfp = &Bs[cur][(wn + lm) * 32 + lq * 8];
    bf16x8 af[2], bfr[2];
#pragma unroll
    for (int i = 0; i < 2; i++)
      af[i] = __builtin_bit_cast(bf16x8,
          *reinterpret_cast<const ushort8*>(afp + i * 16 * 32));
#pragma unroll
    for (int j = 0; j < 2; j++)
      bfr[j] = __builtin_bit_cast(bf16x8,
          *reinterpret_cast<const ushort8*>(bfp + j * 16 * 32));
#pragma unroll
    for (int i = 0; i < 2; i++)
#pragma unroll
      for (int j = 0; j < 2; j++)
        acc[i][j] = __builtin_amdgcn_mfma_f32_16x16x32_bf16(af[i], bfr[j],
                                                            acc[i][j], 0, 0, 0);
    __syncthreads();   // drains this step's LDS reads + next step's staging
  }

  // Epilogue. C/D layout: col = lane&15, row = (lane>>4)*4 + reg.
  const int r0 = bm + wm + lq * 4;
  const int c0 = bn + wn + lm;
#pragma unroll
  for (int j = 0; j < 2; j++) {
    int col = c0 + j * 16;
    float bv = bias[col];
#pragma unroll
    for (int i = 0; i < 2; i++) {
      int rowb = r0 + i * 16;
#pragma unroll
      for (int r = 0; r < 4; r++) {
        int row = rowb + r;
        float v = acc[i][j][r] + bv;
        size_t idx = (size_t)row * N + col;
        if (EPI == 1) {
          ((float*)Cout)[idx] = (col < 512) ? v * v : v;
        } else if (EPI == 2) {
          float g = 0.5f * v * (1.0f + erff(v * 0.70710678118654752f));
          ((unsigned short*)Cout)[idx] = f2bf(g);
        } else {
          ((float*)Cout)[idx] = Cres[idx] + v;
        }
      }
    }
  }
}

// ---------------------------------------------------------------------------
// Per-chunk summaries from fused qkv buffer (row stride 768).
__global__ __launch_bounds__(256) void attn_sums_kernel(
    const float* __restrict__ qkv, float* __restrict__ sums) {
  int blk = blockIdx.x;              // b*(H*NC) + h*NC + c
  int c = blk & (kNC - 1);
  int hh = (blk >> 5) & (kH - 1);
  int b = blk >> 8;
  int g0 = c * kCHUNK;
  __shared__ float ks[kCHUNK][kHD];
  __shared__ float vs[kCHUNK][kHD];
  const float* kbase = qkv + (size_t)(b * kG + g0) * kQKVN + 256 + hh * kHD;
  const float* vbase = qkv + (size_t)(b * kG + g0) * kQKVN + 512 + hh * kHD;
#pragma unroll
  for (int r = 0; r < 2; r++) {
    int e = threadIdx.x + r * 256;
    int i = e >> 3, j = (e & 7) * 4;
    *(float4*)&ks[i][j] = *(const float4*)&kbase[(size_t)i * kQKVN + j];
    *(float4*)&vs[i][j] = *(const float4*)&vbase[(size_t)i * kQKVN + j];
  }
  __syncthreads();
  int m = threadIdx.x >> 3, n0 = (threadIdx.x & 7) * 4;
  float a0 = 0, a1 = 0, a2 = 0, a3 = 0;
  for (int i = 0; i < kCHUNK; i++) {
    float km = ks[i][m];
    float4 v4 = *(const float4*)&vs[i][n0];
    a0 = fmaf(km, v4.x, a0); a1 = fmaf(km, v4.y, a1);
    a2 = fmaf(km, v4.z, a2); a3 = fmaf(km, v4.w, a3);
  }
  float* outp = sums + (size_t)blk * kSUMSZ;
  *(float4*)&outp[m * kHD + n0] = make_float4(a0, a1, a2, a3);
  if (threadIdx.x < kHD) {
    float s = 0;
    for (int i = 0; i < kCHUNK; i++) s += ks[i][threadIdx.x];
    outp[kHD * kHD + threadIdx.x] = s;
  }
}

// ---------------------------------------------------------------------------
// Exclusive prefix scan over chunks. Batched loads (independent, pipelined),
// register prefix, batched stores. grid = kB*kH*5, block = 256.
__global__ void attn_scan_kernel(float* __restrict__ sums) {
  int bh = blockIdx.x / 5, part = blockIdx.x % 5;
  int e = part * 256 + threadIdx.x;
  if (e >= kSUMSZ) return;
  float* base = sums + (size_t)bh * kNC * kSUMSZ + e;
  float v[kNC];
#pragma unroll
  for (int c = 0; c < kNC; c++) v[c] = base[(size_t)c * kSUMSZ];
  float run = 0;
#pragma unroll
  for (int c = 0; c < kNC; c++) {
    float tv = v[c];
    base[(size_t)c * kSUMSZ] = run;
    run += tv;
  }
}

// ---------------------------------------------------------------------------
// Per-chunk output: o = (QK^T masked)·V + Q·S_prev, normalized; h += o
// Conflict-free LDS layout: q/k/v stride 36, Amat stride 68; den folded into
// the A-build stage (reuses q registers, shfl reduce over the 4 j-lanes).
__global__ __launch_bounds__(256) void attn_out_kernel(
    const float* __restrict__ qkv, const float* __restrict__ sums,
    float* __restrict__ h) {
  int blk = blockIdx.x;
  int c = blk & (kNC - 1);
  int hh = (blk >> 5) & (kH - 1);
  int b = blk >> 8;
  int g0 = c * kCHUNK;
  __shared__ float qs[kCHUNK][36];
  __shared__ float ks[kCHUNK][36];
  __shared__ float vs[kCHUNK][36];
  __shared__ float Sf[kHD][kHD];
  __shared__ float ksum[kHD];
  __shared__ float dinv_s[kCHUNK];
  __shared__ float Amat[kCHUNK][68];
  int t = threadIdx.x;
  const float* base = qkv + (size_t)(b * kG + g0) * kQKVN + hh * kHD;
#pragma unroll
  for (int r = 0; r < 2; r++) {
    int e = t + r * 256;
    int i = e >> 3, j = (e & 7) * 4;
    *(float4*)&qs[i][j] = *(const float4*)&base[(size_t)i * kQKVN + j];
    *(float4*)&ks[i][j] = *(const float4*)&base[(size_t)i * kQKVN + 256 + j];
    *(float4*)&vs[i][j] = *(const float4*)&base[(size_t)i * kQKVN + 512 + j];
  }
  const float* sp = sums + (size_t)blk * kSUMSZ;
  *(float4*)&((float*)Sf)[t * 4] = *(const float4*)&sp[t * 4];
  if (t < 8) *(float4*)&ksum[t * 4] = *(const float4*)&sp[kHD * kHD + t * 4];
  __syncthreads();

  // Stage 1: Amat[i][j] = q_i . k_j, plus den_i folded in.
  {
    int i = t >> 2, jb = t & 3;
    float qr[kHD];
#pragma unroll
    for (int m4 = 0; m4 < kHD / 4; m4++) {
      float4 qv = *(const float4*)&qs[i][m4 * 4];
      qr[m4 * 4 + 0] = qv.x; qr[m4 * 4 + 1] = qv.y;
      qr[m4 * 4 + 2] = qv.z; qr[m4 * 4 + 3] = qv.w;
    }
    float psum = 0.0f;
#pragma unroll
    for (int jj = 0; jj < 16; jj++) {
      int j = jb + jj * 4;
      float s = 0;
#pragma unroll
      for (int m4 = 0; m4 < kHD / 4; m4++) {
        float4 kv = *(const float4*)&ks[j][m4 * 4];
        s = fmaf(qr[m4 * 4 + 0], kv.x, s);
        s = fmaf(qr[m4 * 4 + 1], kv.y, s);
        s = fmaf(qr[m4 * 4 + 2], kv.z, s);
        s = fmaf(qr[m4 * 4 + 3], kv.w, s);
      }
      Amat[i][j] = s;
      if (j <= i) psum += s;
    }
    psum += __shfl_xor(psum, 1);
    psum += __shfl_xor(psum, 2);
    if (jb == 0) {
      float dk = 0;
#pragma unroll
      for (int m = 0; m < kHD; m++) dk = fmaf(qr[m], ksum[m], dk);
      dinv_s[i] = 1.0f / (psum + dk + 1e-16f);
    }
  }
  __syncthreads();

  // Stage 2: num_i[n] = sum_{j<=i} A[i][j] v_j[n] + q_i . S ; h += num * dinv
  float* hbase = h + (size_t)(b * kG + g0) * kD + hh * kHD;
#pragma unroll
  for (int uu = 0; uu < 2; uu++) {
    int u = t + uu * 256;
    int i = u >> 3, n0 = (u & 7) * 4;
    float ax = 0, ay = 0, az = 0, aw = 0;
#pragma unroll
    for (int m = 0; m < kHD; m++) {
      float qm = qs[i][m];
      float4 s4 = *(const float4*)&Sf[m][n0];
      ax = fmaf(qm, s4.x, ax); ay = fmaf(qm, s4.y, ay);
      az = fmaf(qm, s4.z, az); aw = fmaf(qm, s4.w, aw);
    }
    for (int j = 0; j <= i; j++) {
      float w = Amat[i][j];
      float4 vv = *(const float4*)&vs[j][n0];
      ax = fmaf(w, vv.x, ax); ay = fmaf(w, vv.y, ay);
      az = fmaf(w, vv.z, az); aw = fmaf(w, vv.w, aw);
    }
    float dinv = dinv_s[i];
    float* hp = hbase + (size_t)i * kD + n0;
    float4 old = *(const float4*)hp;
    *(float4*)hp = make_float4(old.x + ax * dinv, old.y + ay * dinv,
                               old.z + az * dinv, old.w + aw * dinv);
  }
}

// ---------------------------------------------------------------------------
// out[row] = h[row,:] . Wo + bo. Wave-per-row, 4 rows/block.
__global__ __launch_bounds__(256) void final_kernel(
    const float* __restrict__ h, const float* __restrict__ Wo,
    const float* __restrict__ bo, float* __restrict__ out) {
  int w = threadIdx.x >> 6, lane = threadIdx.x & 63;
  size_t row = (size_t)blockIdx.x * 4 + w;
  float4 hv = *(const float4*)&h[row * kD + lane * 4];
  float4 wv = *(const float4*)&Wo[lane * 4];
  float s = hv.x * wv.x + hv.y * wv.y + hv.z * wv.z + hv.w * wv.w;
#pragma unroll
  for (int o = 32; o > 0; o >>= 1) s += __shfl_xor(s, o);
  if (lane == 0) out[row] = s + bo[0];
}

// ---------------------------------------------------------------------------
extern "C" void kernel_launch(void* const* d_in, const int* in_sizes, int n_in,
                              void* d_out, int out_size, void* d_ws, size_t ws_size,
                              hipStream_t stream) {
  const float* x    = (const float*)d_in[0];
  const float* ge   = (const float*)d_in[1];
  const float* Wq   = (const float*)d_in[2];
  const float* bq   = (const float*)d_in[3];
  const float* Wk   = (const float*)d_in[4];
  const float* bk   = (const float*)d_in[5];
  const float* Wv   = (const float*)d_in[6];
  const float* bv   = (const float*)d_in[7];
  const float* ln1g = (const float*)d_in[8];
  const float* ln1b = (const float*)d_in[9];
  const float* ln2g = (const float*)d_in[10];
  const float* ln2b = (const float*)d_in[11];
  const float* WU   = (const float*)d_in[12];
  const float* bU   = (const float*)d_in[13];
  const float* WV   = (const float*)d_in[14];
  const float* bV   = (const float*)d_in[15];
  const float* Wo   = (const float*)d_in[16];
  const float* bo   = (const float*)d_in[17];
  float* out = (float*)d_out;

  // Workspace layout (fp32 slot offsets; all 16B-aligned):
  float* ws = (float*)d_ws;
  float*          h       = ws;                        // 2,097,152 f32
  unsigned short* zb      = (unsigned short*)(ws + 2097152);   // 2,097,152 bf16
  float*          qkv     = ws + 3145728;              // 6,291,456 f32 [8192][768]
  unsigned short* u       = (unsigned short*)qkv;      // aliases qkv (disjoint phases)
  float*          sums    = ws + 9437184;              // 1,081,344 f32
  unsigned short* Wqkv_t  = (unsigned short*)(ws + 10518528);  // 786,432 bf16
  unsigned short* WU_t    = (unsigned short*)(ws + 10911744);  // 1,048,576 bf16
  unsigned short* WV_t    = (unsigned short*)(ws + 11436032);  // 1,048,576 bf16
  float*          bias_qkv= ws + 11960320;             // 3,072 f32

  dim3 blk256(256);
  convert_weights_kernel<<<kL * 704 + 12, blk256, 0, stream>>>(
      Wq, Wk, Wv, WU, WV, bq, bk, bv, Wqkv_t, WU_t, WV_t, bias_qkv);
  embed_kernel<<<kBG * kD / 256, blk256, 0, stream>>>(x, ge, h);
  for (int l = 0; l < kL; l++) {
    ln_kernel<<<kBG / 4, blk256, 0, stream>>>(h, ln1g + l * kD, ln1b + l * kD, zb);
    mfma_gemm<1><<<dim3(kQKVN / 64, kBG / 64), blk256, 0, stream>>>(
        zb, Wqkv_t + (size_t)l * kQKVN * kD, bias_qkv + l * kQKVN, qkv, nullptr,
        kBG, kQKVN, kD);
    attn_sums_kernel<<<kB * kH * kNC, blk256, 0, stream>>>(qkv, sums);
    attn_scan_kernel<<<kB * kH * 5, blk256, 0, stream>>>(sums);
    attn_out_kernel<<<kB * kH * kNC, blk256, 0, stream>>>(qkv, sums, h);
    ln_kernel<<<kBG / 4, blk256, 0, stream>>>(h, ln2g + l * kD, ln2b + l * kD, zb);
    mfma_gemm<2><<<dim3(kFFN / 64, kBG / 64), blk256, 0, stream>>>(
        zb, WU_t + (size_t)l * kFFN * kD, bU + l * kFFN, u, nullptr,
        kBG, kFFN, kD);
    mfma_gemm<3><<<dim3(kD / 64, kBG / 64), blk256, 0, stream>>>(
        u, WV_t + (size_t)l * kD * kFFN, bV + l * kD, h, h,
        kBG, kD, kFFN);
  }
  final_kernel<<<kBG / 4, blk256, 0, stream>>>(h, Wo, bo, out);
}